// Round 1
// baseline (516.897 us; speedup 1.0000x reference)
//
#include <hip/hip_runtime.h>
#include <hip/hip_fp16.h>

// Problem constants
#define B_SZ  4096
#define DIN   1024
#define DH    2048
#define K_TOT 3072      // DIN + DH
#define N_TOT 8192      // 4 * DH

// GEMM tile
#define BM 128
#define BN 128          // = 32 hidden units * 4 gates (interleaved layout)
#define BK 32

typedef _Float16 half8 __attribute__((ext_vector_type(8)));
typedef _Float16 half4 __attribute__((ext_vector_type(4)));
typedef float   float4v __attribute__((ext_vector_type(4)));

// ---------- async global->LDS (16B per lane, wave-uniform LDS base) ----------
__device__ __forceinline__ void load_lds16(const void* g, void* l) {
    __builtin_amdgcn_global_load_lds(
        (const __attribute__((address_space(1))) void*)g,
        (__attribute__((address_space(3))) void*)l,
        16, 0, 0);
}

// ---------- cast x|h_prev -> A [B_SZ, K_TOT] fp16 ----------
__global__ __launch_bounds__(256) void cast_A_kernel(
        const float* __restrict__ x, const float* __restrict__ h,
        _Float16* __restrict__ A) {
    int idx = (blockIdx.x * 256 + threadIdx.x) * 4;   // element index in A
    int b = idx / K_TOT;
    int c = idx - b * K_TOT;
    const float* src = (c < DIN) ? (x + b * DIN + c) : (h + b * DH + (c - DIN));
    float4 v = *reinterpret_cast<const float4*>(src);
    half4 o;
    o.x = (_Float16)v.x; o.y = (_Float16)v.y;
    o.z = (_Float16)v.z; o.w = (_Float16)v.w;
    *reinterpret_cast<half4*>(A + idx) = o;
}

// ---------- cast W|R -> Wb [N_TOT, K_TOT] fp16, gate-interleaved ----------
// Row n: gate g = (n>>5)&3, hidden j = (n>>7)*32 + (n&31).
// So every 128-row block = [32 z rows | 32 i rows | 32 f rows | 32 o rows].
__global__ __launch_bounds__(256) void cast_W_kernel(
        const float* __restrict__ Wz, const float* __restrict__ Wi,
        const float* __restrict__ Wf, const float* __restrict__ Wo,
        const float* __restrict__ Rz, const float* __restrict__ Ri,
        const float* __restrict__ Rf, const float* __restrict__ Ro,
        _Float16* __restrict__ Wb) {
    int idx = (blockIdx.x * 256 + threadIdx.x) * 4;   // element index in Wb
    int n = idx / K_TOT;
    int c = idx - n * K_TOT;
    int g = (n >> 5) & 3;
    int j = ((n >> 7) << 5) | (n & 31);
    const float* W = (g == 0) ? Wz : (g == 1) ? Wi : (g == 2) ? Wf : Wo;
    const float* R = (g == 0) ? Rz : (g == 1) ? Ri : (g == 2) ? Rf : Ro;
    const float* src = (c < DIN) ? (W + j * DIN + c) : (R + j * DH + (c - DIN));
    float4 v = *reinterpret_cast<const float4*>(src);
    half4 o;
    o.x = (_Float16)v.x; o.y = (_Float16)v.y;
    o.z = (_Float16)v.z; o.w = (_Float16)v.w;
    *reinterpret_cast<half4*>(Wb + idx) = o;
}

// ---------- fused GEMM + sLSTM pointwise epilogue ----------
// Block: 256 threads = 4 waves. Wave w owns rows [32w, 32w+32) of the 128-row
// M-tile, all 128 N-columns (2 m-frags x 8 n-frags of 16x16x32 MFMA).
// N-tile covers 32 hidden units; n-frags {0,1}=z {2,3}=i {4,5}=f {6,7}=o, so
// all 4 gates of one output live in the same lane/reg -> epilogue is per-lane.
__global__ __launch_bounds__(256) void slstm_gemm_kernel(
        const _Float16* __restrict__ A, const _Float16* __restrict__ Wb,
        const float* __restrict__ c_prev, const float* __restrict__ n_prev,
        const float* __restrict__ bz, const float* __restrict__ bi,
        const float* __restrict__ bf, const float* __restrict__ bo,
        float* __restrict__ Hout) {
    __shared__ __align__(16) _Float16 As[BM * BK];
    __shared__ __align__(16) _Float16 Bs[BN * BK];

    const int ntile = blockIdx.x;          // 0..63  (hidden base = 32*ntile)
    const int mtile = blockIdx.y;          // 0..31
    const int tid  = threadIdx.x;
    const int wv   = tid >> 6;
    const int l    = tid & 63;
    const int quad = l >> 4;
    const int l16  = l & 15;

    const int m0 = mtile * BM;
    const int n0 = ntile * BN;

    float4v acc[2][8];
#pragma unroll
    for (int i = 0; i < 2; i++)
#pragma unroll
        for (int j = 0; j < 8; j++) acc[i][j] = (float4v){0.f, 0.f, 0.f, 0.f};

    // Staging: 8 chunks of 1024B per tile; wave wv stages chunks {2wv, 2wv+1}.
    // Lane l's 16B -> LDS base + l*16 == row (chunk*16 + l/4), halves (l%4)*8.
    const int chunk0 = wv * 2;
    const int srow0  = chunk0 * 16 + (l >> 2);
    const int srow1  = srow0 + 16;
    const int skoff  = (l & 3) * 8;

    const _Float16* Ag0 = A  + (size_t)(m0 + srow0) * K_TOT + skoff;
    const _Float16* Ag1 = A  + (size_t)(m0 + srow1) * K_TOT + skoff;
    const _Float16* Bg0 = Wb + (size_t)(n0 + srow0) * K_TOT + skoff;
    const _Float16* Bg1 = Wb + (size_t)(n0 + srow1) * K_TOT + skoff;

    _Float16* AsL0 = As + chunk0 * 512;
    _Float16* AsL1 = As + (chunk0 + 1) * 512;
    _Float16* BsL0 = Bs + chunk0 * 512;
    _Float16* BsL1 = Bs + (chunk0 + 1) * 512;

    for (int kt = 0; kt < K_TOT; kt += BK) {
        load_lds16(Ag0 + kt, AsL0);
        load_lds16(Ag1 + kt, AsL1);
        load_lds16(Bg0 + kt, BsL0);
        load_lds16(Bg1 + kt, BsL1);
        __syncthreads();

        // A-operand frag: row m = lane&15, k = quad*8..+8  (b128 reads)
        half8 afr0 = *reinterpret_cast<const half8*>(As + (wv * 32 + l16) * BK + quad * 8);
        half8 afr1 = *reinterpret_cast<const half8*>(As + (wv * 32 + 16 + l16) * BK + quad * 8);
        half8 bfr[8];
#pragma unroll
        for (int nf = 0; nf < 8; nf++)
            bfr[nf] = *reinterpret_cast<const half8*>(Bs + (nf * 16 + l16) * BK + quad * 8);

#pragma unroll
        for (int nf = 0; nf < 8; nf++) {
            acc[0][nf] = __builtin_amdgcn_mfma_f32_16x16x32_f16(afr0, bfr[nf], acc[0][nf], 0, 0, 0);
            acc[1][nf] = __builtin_amdgcn_mfma_f32_16x16x32_f16(afr1, bfr[nf], acc[1][nf], 0, 0, 0);
        }
        __syncthreads();
    }

    // Epilogue: C/D layout col=lane&15, row=quad*4+reg.
    const int j_base = ntile * 32;
#pragma unroll
    for (int nf = 0; nf < 2; nf++) {
        const int j = j_base + nf * 16 + l16;
        const float bzv = bz[j], biv = bi[j], bfv = bf[j], bov = bo[j];
#pragma unroll
        for (int mf = 0; mf < 2; mf++) {
#pragma unroll
            for (int r = 0; r < 4; r++) {
                const int row = m0 + wv * 32 + mf * 16 + quad * 4 + r;
                const size_t off = (size_t)row * DH + j;
                float az  = acc[mf][nf][r]     + bzv;
                float ai  = acc[mf][nf + 2][r] + biv;
                float af_ = acc[mf][nf + 4][r] + bfv;
                float ao  = acc[mf][nf + 6][r] + bov;
                float z  = tanhf(az);
                float iv = __expf(ai);
                float fv = __expf(af_);
                float ov = 1.0f / (1.0f + __expf(-ao));
                float cc = fv * c_prev[off] + iv * z;
                float nn = fv * n_prev[off] + iv;
                Hout[off] = ov * (cc / nn);
            }
        }
    }
}

extern "C" void kernel_launch(void* const* d_in, const int* in_sizes, int n_in,
                              void* d_out, int out_size, void* d_ws, size_t ws_size,
                              hipStream_t stream) {
    const float* x      = (const float*)d_in[0];
    const float* h_prev = (const float*)d_in[1];
    const float* c_prev = (const float*)d_in[2];
    const float* n_prev = (const float*)d_in[3];
    const float* Wz = (const float*)d_in[4];
    const float* Wi = (const float*)d_in[5];
    const float* Wf = (const float*)d_in[6];
    const float* Wo = (const float*)d_in[7];
    const float* bz = (const float*)d_in[8];
    const float* bi = (const float*)d_in[9];
    const float* bf = (const float*)d_in[10];
    const float* bo = (const float*)d_in[11];
    const float* Rz = (const float*)d_in[12];
    const float* Ri = (const float*)d_in[13];
    const float* Rf = (const float*)d_in[14];
    const float* Ro = (const float*)d_in[15];

    _Float16* A  = (_Float16*)d_ws;                       // [B_SZ, K_TOT]
    _Float16* Wb = A + (size_t)B_SZ * K_TOT;              // [N_TOT, K_TOT]

    cast_A_kernel<<<(B_SZ * K_TOT / 4) / 256, 256, 0, stream>>>(x, h_prev, A);
    cast_W_kernel<<<(N_TOT * K_TOT / 4) / 256, 256, 0, stream>>>(
        Wz, Wi, Wf, Wo, Rz, Ri, Rf, Ro, Wb);

    dim3 grid(N_TOT / BN, B_SZ / BM);   // (64, 32) = 2048 blocks
    slstm_gemm_kernel<<<grid, 256, 0, stream>>>(
        A, Wb, c_prev, n_prev, bz, bi, bf, bo, (float*)d_out);
}

// Round 2
// 480.817 us; speedup vs baseline: 1.0750x; 1.0750x over previous
//
#include <hip/hip_runtime.h>
#include <hip/hip_fp16.h>

// Problem constants
#define B_SZ  4096
#define DIN   1024
#define DH    2048
#define K_TOT 3072      // DIN + DH
#define N_TOT 8192      // 4 * DH

// GEMM tile
#define BM 128
#define BN 128          // = 32 hidden units * 4 gates, interleaved [16z|16i|16f|16o] per 64 cols
#define BK 32

typedef _Float16 half8 __attribute__((ext_vector_type(8)));
typedef float   float4v __attribute__((ext_vector_type(4)));

// ---------- async global->LDS (16B per lane, wave-uniform LDS base) ----------
__device__ __forceinline__ void load_lds16(const void* g, void* l) {
    __builtin_amdgcn_global_load_lds(
        (const __attribute__((address_space(1))) void*)g,
        (__attribute__((address_space(3))) void*)l,
        16, 0, 0);
}

// ---------- cast x|h_prev -> A [B_SZ, K_TOT] fp16 (8 elems/thread, 16B store) ----------
__global__ __launch_bounds__(256) void cast_A_kernel(
        const float* __restrict__ x, const float* __restrict__ h,
        _Float16* __restrict__ A) {
    int idx = (blockIdx.x * 256 + threadIdx.x) * 8;
    int b = idx / K_TOT;
    int c = idx - b * K_TOT;
    // 8-element group never straddles the DIN boundary (1024 % 8 == 0)
    const float* src = (c < DIN) ? (x + (size_t)b * DIN + c)
                                 : (h + (size_t)b * DH + (c - DIN));
    float4 v0 = *reinterpret_cast<const float4*>(src);
    float4 v1 = *reinterpret_cast<const float4*>(src + 4);
    half8 o;
    o[0] = (_Float16)v0.x; o[1] = (_Float16)v0.y;
    o[2] = (_Float16)v0.z; o[3] = (_Float16)v0.w;
    o[4] = (_Float16)v1.x; o[5] = (_Float16)v1.y;
    o[6] = (_Float16)v1.z; o[7] = (_Float16)v1.w;
    *reinterpret_cast<half8*>(A + idx) = o;
}

// ---------- cast W|R -> Wb [N_TOT, K_TOT] fp16, gate-interleaved @16 ----------
// Row n: tile = n>>7 (32 hidden units each); within tile t = n&127:
//   gate g = (t>>4)&3, hidden j = tile*32 + (t>>6)*16 + (t&15)
// => every 64-row group = [16 z | 16 i | 16 f | 16 o] rows.
__global__ __launch_bounds__(256) void cast_W_kernel(
        const float* __restrict__ Wz, const float* __restrict__ Wi,
        const float* __restrict__ Wf, const float* __restrict__ Wo,
        const float* __restrict__ Rz, const float* __restrict__ Ri,
        const float* __restrict__ Rf, const float* __restrict__ Ro,
        _Float16* __restrict__ Wb) {
    int idx = (blockIdx.x * 256 + threadIdx.x) * 8;
    int n = idx / K_TOT;
    int c = idx - n * K_TOT;
    int t = n & 127;
    int g = (t >> 4) & 3;
    int j = ((n >> 7) << 5) + ((t >> 6) << 4) + (t & 15);
    const float* W = (g == 0) ? Wz : (g == 1) ? Wi : (g == 2) ? Wf : Wo;
    const float* R = (g == 0) ? Rz : (g == 1) ? Ri : (g == 2) ? Rf : Ro;
    const float* src = (c < DIN) ? (W + (size_t)j * DIN + c)
                                 : (R + (size_t)j * DH + (c - DIN));
    float4 v0 = *reinterpret_cast<const float4*>(src);
    float4 v1 = *reinterpret_cast<const float4*>(src + 4);
    half8 o;
    o[0] = (_Float16)v0.x; o[1] = (_Float16)v0.y;
    o[2] = (_Float16)v0.z; o[3] = (_Float16)v0.w;
    o[4] = (_Float16)v1.x; o[5] = (_Float16)v1.y;
    o[6] = (_Float16)v1.z; o[7] = (_Float16)v1.w;
    *reinterpret_cast<half8*>(Wb + idx) = o;
}

// ---------- fused GEMM + sLSTM pointwise epilogue (m97 4x4 wave shape) ----------
// Block: 256 threads = 4 waves arranged 2x2; wave (wm,wn) owns 64x64:
//   4 A-frags (rows wm*64+mf*16) x 4 B-frags (cols wn*64+nf*16) -> acc[4][4].
// With the @16 gate interleave, nf IS the gate index and the hidden unit
// j = ntile*32 + wn*16 + (lane&15) is uniform over nf -> per-lane gate math.
__global__ __launch_bounds__(256) void slstm_gemm_kernel(
        const _Float16* __restrict__ A, const _Float16* __restrict__ Wb,
        const float* __restrict__ c_prev, const float* __restrict__ n_prev,
        const float* __restrict__ bz, const float* __restrict__ bi,
        const float* __restrict__ bf, const float* __restrict__ bo,
        float* __restrict__ Hout) {
    __shared__ __align__(16) _Float16 As[BM * BK];
    __shared__ __align__(16) _Float16 Bs[BN * BK];

    const int ntile = blockIdx.x;          // 0..63  (hidden base = 32*ntile)
    const int mtile = blockIdx.y;          // 0..31
    const int tid  = threadIdx.x;
    const int wv   = tid >> 6;
    const int wm   = wv >> 1;              // 0..1
    const int wn   = wv & 1;               // 0..1
    const int l    = tid & 63;
    const int quad = l >> 4;
    const int l16  = l & 15;

    const int m0 = mtile * BM;
    const int n0 = ntile * BN;

    float4v acc[4][4];
#pragma unroll
    for (int i = 0; i < 4; i++)
#pragma unroll
        for (int j = 0; j < 4; j++) acc[i][j] = (float4v){0.f, 0.f, 0.f, 0.f};

    // Staging: 8 chunks of 1024B per tile; wave wv stages chunks {2wv, 2wv+1}
    // of both As and Bs. Lane l -> row (chunk*16 + l/4), k-halfs (l%4)*8.
    const int chunk0 = wv * 2;
    const int srow0  = chunk0 * 16 + (l >> 2);
    const int srow1  = srow0 + 16;
    const int skoff  = (l & 3) * 8;

    const _Float16* Ag0 = A  + (size_t)(m0 + srow0) * K_TOT + skoff;
    const _Float16* Ag1 = A  + (size_t)(m0 + srow1) * K_TOT + skoff;
    const _Float16* Bg0 = Wb + (size_t)(n0 + srow0) * K_TOT + skoff;
    const _Float16* Bg1 = Wb + (size_t)(n0 + srow1) * K_TOT + skoff;

    _Float16* AsL0 = As + chunk0 * 512;
    _Float16* AsL1 = As + (chunk0 + 1) * 512;
    _Float16* BsL0 = Bs + chunk0 * 512;
    _Float16* BsL1 = Bs + (chunk0 + 1) * 512;

    for (int kt = 0; kt < K_TOT; kt += BK) {
        load_lds16(Ag0 + kt, AsL0);
        load_lds16(Ag1 + kt, AsL1);
        load_lds16(Bg0 + kt, BsL0);
        load_lds16(Bg1 + kt, BsL1);
        __syncthreads();

        // A-operand frag: row m = lane&15, k = quad*8..+8  (ds_read_b128)
        half8 afr[4], bfr[4];
#pragma unroll
        for (int mf = 0; mf < 4; mf++)
            afr[mf] = *reinterpret_cast<const half8*>(As + (wm * 64 + mf * 16 + l16) * BK + quad * 8);
#pragma unroll
        for (int nf = 0; nf < 4; nf++)
            bfr[nf] = *reinterpret_cast<const half8*>(Bs + (wn * 64 + nf * 16 + l16) * BK + quad * 8);

#pragma unroll
        for (int mf = 0; mf < 4; mf++)
#pragma unroll
            for (int nf = 0; nf < 4; nf++)
                acc[mf][nf] = __builtin_amdgcn_mfma_f32_16x16x32_f16(afr[mf], bfr[nf], acc[mf][nf], 0, 0, 0);
        __syncthreads();
    }

    // Epilogue: C/D layout col=lane&15, row=quad*4+reg. nf = gate.
    const int j = ntile * 32 + wn * 16 + l16;   // hidden unit, uniform over nf/mf
    const float bzv = bz[j], biv = bi[j], bfv = bf[j], bov = bo[j];
#pragma unroll
    for (int mf = 0; mf < 4; mf++) {
#pragma unroll
        for (int r = 0; r < 4; r++) {
            const int row = m0 + wm * 64 + mf * 16 + quad * 4 + r;
            const size_t off = (size_t)row * DH + j;
            const float az  = acc[mf][0][r] + bzv;
            const float ai  = acc[mf][1][r] + biv;
            const float af_ = acc[mf][2][r] + bfv;
            const float ao  = acc[mf][3][r] + bov;
            // tanh via exp, sign-safe (e2 <= 1 always; no inf/inf)
            const float ax = fabsf(az);
            const float e2 = __expf(-2.0f * ax);
            float tz = __fdividef(1.0f - e2, 1.0f + e2);
            tz = (az >= 0.0f) ? tz : -tz;
            const float iv = __expf(ai);
            const float fv = __expf(af_);
            const float ov = __fdividef(1.0f, 1.0f + __expf(-ao));
            const float cc = fv * c_prev[off] + iv * tz;
            const float nn = fv * n_prev[off] + iv;
            Hout[off] = ov * __fdividef(cc, nn);
        }
    }
}

extern "C" void kernel_launch(void* const* d_in, const int* in_sizes, int n_in,
                              void* d_out, int out_size, void* d_ws, size_t ws_size,
                              hipStream_t stream) {
    const float* x      = (const float*)d_in[0];
    const float* h_prev = (const float*)d_in[1];
    const float* c_prev = (const float*)d_in[2];
    const float* n_prev = (const float*)d_in[3];
    const float* Wz = (const float*)d_in[4];
    const float* Wi = (const float*)d_in[5];
    const float* Wf = (const float*)d_in[6];
    const float* Wo = (const float*)d_in[7];
    const float* bz = (const float*)d_in[8];
    const float* bi = (const float*)d_in[9];
    const float* bf = (const float*)d_in[10];
    const float* bo = (const float*)d_in[11];
    const float* Rz = (const float*)d_in[12];
    const float* Ri = (const float*)d_in[13];
    const float* Rf = (const float*)d_in[14];
    const float* Ro = (const float*)d_in[15];

    _Float16* A  = (_Float16*)d_ws;                       // [B_SZ, K_TOT]
    _Float16* Wb = A + (size_t)B_SZ * K_TOT;              // [N_TOT, K_TOT]

    cast_A_kernel<<<(B_SZ * K_TOT / 8) / 256, 256, 0, stream>>>(x, h_prev, A);
    cast_W_kernel<<<(N_TOT * K_TOT / 8) / 256, 256, 0, stream>>>(
        Wz, Wi, Wf, Wo, Rz, Ri, Rf, Ro, Wb);

    dim3 grid(N_TOT / BN, B_SZ / BM);   // (64, 32) = 2048 blocks
    slstm_gemm_kernel<<<grid, 256, 0, stream>>>(
        A, Wb, c_prev, n_prev, bz, bi, bf, bo, (float*)d_out);
}

// Round 3
// 478.616 us; speedup vs baseline: 1.0800x; 1.0046x over previous
//
#include <hip/hip_runtime.h>
#include <hip/hip_fp16.h>

// Problem constants
#define B_SZ  4096
#define DIN   1024
#define DH    2048
#define K_TOT 3072      // DIN + DH
#define N_TOT 8192      // 4 * DH

// GEMM tile
#define BM 128
#define BN 128          // = 32 hidden units * 4 gates, interleaved [16z|16i|16f|16o] per 64 cols
#define BK 32

typedef _Float16 half8 __attribute__((ext_vector_type(8)));
typedef float   float4v __attribute__((ext_vector_type(4)));

// ---------- async global->LDS (16B per lane, wave-uniform LDS base) ----------
__device__ __forceinline__ void load_lds16(const void* g, void* l) {
    __builtin_amdgcn_global_load_lds(
        (const __attribute__((address_space(1))) void*)g,
        (__attribute__((address_space(3))) void*)l,
        16, 0, 0);
}

// ---------- cast x|h_prev -> A [B_SZ, K_TOT] fp16 (8 elems/thread, 16B store) ----------
__global__ __launch_bounds__(256) void cast_A_kernel(
        const float* __restrict__ x, const float* __restrict__ h,
        _Float16* __restrict__ A) {
    int idx = (blockIdx.x * 256 + threadIdx.x) * 8;
    int b = idx / K_TOT;
    int c = idx - b * K_TOT;
    // 8-element group never straddles the DIN boundary (1024 % 8 == 0)
    const float* src = (c < DIN) ? (x + (size_t)b * DIN + c)
                                 : (h + (size_t)b * DH + (c - DIN));
    float4 v0 = *reinterpret_cast<const float4*>(src);
    float4 v1 = *reinterpret_cast<const float4*>(src + 4);
    half8 o;
    o[0] = (_Float16)v0.x; o[1] = (_Float16)v0.y;
    o[2] = (_Float16)v0.z; o[3] = (_Float16)v0.w;
    o[4] = (_Float16)v1.x; o[5] = (_Float16)v1.y;
    o[6] = (_Float16)v1.z; o[7] = (_Float16)v1.w;
    *reinterpret_cast<half8*>(A + idx) = o;
}

// ---------- cast W|R -> Wb [N_TOT, K_TOT] fp16, gate-interleaved @16 ----------
// Row n: tile = n>>7 (32 hidden units each); within tile t = n&127:
//   gate g = (t>>4)&3, hidden j = tile*32 + (t>>6)*16 + (t&15)
// => every 64-row group = [16 z | 16 i | 16 f | 16 o] rows.
__global__ __launch_bounds__(256) void cast_W_kernel(
        const float* __restrict__ Wz, const float* __restrict__ Wi,
        const float* __restrict__ Wf, const float* __restrict__ Wo,
        const float* __restrict__ Rz, const float* __restrict__ Ri,
        const float* __restrict__ Rf, const float* __restrict__ Ro,
        _Float16* __restrict__ Wb) {
    int idx = (blockIdx.x * 256 + threadIdx.x) * 8;
    int n = idx / K_TOT;
    int c = idx - n * K_TOT;
    int t = n & 127;
    int g = (t >> 4) & 3;
    int j = ((n >> 7) << 5) + ((t >> 6) << 4) + (t & 15);
    const float* W = (g == 0) ? Wz : (g == 1) ? Wi : (g == 2) ? Wf : Wo;
    const float* R = (g == 0) ? Rz : (g == 1) ? Ri : (g == 2) ? Rf : Ro;
    const float* src = (c < DIN) ? (W + (size_t)j * DIN + c)
                                 : (R + (size_t)j * DH + (c - DIN));
    float4 v0 = *reinterpret_cast<const float4*>(src);
    float4 v1 = *reinterpret_cast<const float4*>(src + 4);
    half8 o;
    o[0] = (_Float16)v0.x; o[1] = (_Float16)v0.y;
    o[2] = (_Float16)v0.z; o[3] = (_Float16)v0.w;
    o[4] = (_Float16)v1.x; o[5] = (_Float16)v1.y;
    o[6] = (_Float16)v1.z; o[7] = (_Float16)v1.w;
    *reinterpret_cast<half8*>(Wb + idx) = o;
}

// ---------- fused GEMM + sLSTM pointwise epilogue (m97 4x4 wave shape) ----------
// Block: 256 threads = 4 waves arranged 2x2; wave (wm,wn) owns 64x64:
//   4 A-frags (rows wm*64+mf*16) x 4 B-frags (cols wn*64+nf*16) -> acc[4][4].
// With the @16 gate interleave, nf IS the gate index and the hidden unit
// j = ntile*32 + wn*16 + (lane&15) is uniform over nf -> per-lane gate math.
//
// LDS bank-conflict swizzle: LDS(row, chunk c) holds global chunk c ^ f(row),
// f(row) = (row>>1)&3 (chunk = 16B). Staging folds the xor into the per-lane
// global source offset; fragment reads fold it into a lane-constant k-offset.
// Resulting ds_read_b128 slot pattern is 2-way (free) instead of 8-way.
__global__ __launch_bounds__(256) void slstm_gemm_kernel(
        const _Float16* __restrict__ A, const _Float16* __restrict__ Wb,
        const float* __restrict__ c_prev, const float* __restrict__ n_prev,
        const float* __restrict__ bz, const float* __restrict__ bi,
        const float* __restrict__ bf, const float* __restrict__ bo,
        float* __restrict__ Hout) {
    __shared__ __align__(16) _Float16 As[BM * BK];
    __shared__ __align__(16) _Float16 Bs[BN * BK];

    const int ntile = blockIdx.x;          // 0..63  (hidden base = 32*ntile)
    const int mtile = blockIdx.y;          // 0..31
    const int tid  = threadIdx.x;
    const int wv   = tid >> 6;
    const int wm   = wv >> 1;              // 0..1
    const int wn   = wv & 1;               // 0..1
    const int l    = tid & 63;
    const int quad = l >> 4;
    const int l16  = l & 15;

    const int m0 = mtile * BM;
    const int n0 = ntile * BN;

    float4v acc[4][4];
#pragma unroll
    for (int i = 0; i < 4; i++)
#pragma unroll
        for (int j = 0; j < 4; j++) acc[i][j] = (float4v){0.f, 0.f, 0.f, 0.f};

    // Staging: 8 chunks of 1024B per tile; wave wv stages chunks {2wv, 2wv+1}
    // of both As and Bs. Lane l -> LDS row (chunk*16 + l/4), chunk-in-row l%4.
    // Swizzled global source chunk = (l&3) ^ f(row); f(row)=(row>>1)&3 and
    // row = chunk*16 + (l>>2) gives f = (l>>3)&3 (chunk*16>>1 ≡ 0 mod 4).
    const int chunk0 = wv * 2;
    const int srow0  = chunk0 * 16 + (l >> 2);
    const int srow1  = srow0 + 16;            // f identical (+16 rows ≡ 0 mod 4 after >>1)
    const int skoff  = (((l & 3) ^ ((l >> 3) & 3)) * 8);

    const _Float16* Ag0 = A  + (size_t)(m0 + srow0) * K_TOT + skoff;
    const _Float16* Ag1 = A  + (size_t)(m0 + srow1) * K_TOT + skoff;
    const _Float16* Bg0 = Wb + (size_t)(n0 + srow0) * K_TOT + skoff;
    const _Float16* Bg1 = Wb + (size_t)(n0 + srow1) * K_TOT + skoff;

    _Float16* AsL0 = As + chunk0 * 512;
    _Float16* AsL1 = As + (chunk0 + 1) * 512;
    _Float16* BsL0 = Bs + chunk0 * 512;
    _Float16* BsL1 = Bs + (chunk0 + 1) * 512;

    // Fragment read k-offset: want global chunk q of row (base16 + l16);
    // stored at LDS chunk q ^ f(row), f = (l16>>1)&3 (base16 ≡ 0 mod 32).
    const int kq = (quad ^ ((l16 >> 1) & 3)) * 8;

    for (int kt = 0; kt < K_TOT; kt += BK) {
        load_lds16(Ag0 + kt, AsL0);
        load_lds16(Ag1 + kt, AsL1);
        load_lds16(Bg0 + kt, BsL0);
        load_lds16(Bg1 + kt, BsL1);
        __syncthreads();

        // A-operand frag: row m = lane&15, k = quad*8..+8  (ds_read_b128)
        half8 afr[4], bfr[4];
#pragma unroll
        for (int mf = 0; mf < 4; mf++)
            afr[mf] = *reinterpret_cast<const half8*>(As + (wm * 64 + mf * 16 + l16) * BK + kq);
#pragma unroll
        for (int nf = 0; nf < 4; nf++)
            bfr[nf] = *reinterpret_cast<const half8*>(Bs + (wn * 64 + nf * 16 + l16) * BK + kq);

#pragma unroll
        for (int mf = 0; mf < 4; mf++)
#pragma unroll
            for (int nf = 0; nf < 4; nf++)
                acc[mf][nf] = __builtin_amdgcn_mfma_f32_16x16x32_f16(afr[mf], bfr[nf], acc[mf][nf], 0, 0, 0);
        __syncthreads();
    }

    // Epilogue: C/D layout col=lane&15, row=quad*4+reg. nf = gate.
    const int j = ntile * 32 + wn * 16 + l16;   // hidden unit, uniform over nf/mf
    const float bzv = bz[j], biv = bi[j], bfv = bf[j], bov = bo[j];
#pragma unroll
    for (int mf = 0; mf < 4; mf++) {
#pragma unroll
        for (int r = 0; r < 4; r++) {
            const int row = m0 + wm * 64 + mf * 16 + quad * 4 + r;
            const size_t off = (size_t)row * DH + j;
            const float az  = acc[mf][0][r] + bzv;
            const float ai  = acc[mf][1][r] + biv;
            const float af_ = acc[mf][2][r] + bfv;
            const float ao  = acc[mf][3][r] + bov;
            // tanh via exp, sign-safe (e2 <= 1 always; no inf/inf)
            const float ax = fabsf(az);
            const float e2 = __expf(-2.0f * ax);
            float tz = __fdividef(1.0f - e2, 1.0f + e2);
            tz = (az >= 0.0f) ? tz : -tz;
            const float iv = __expf(ai);
            const float fv = __expf(af_);
            const float ov = __fdividef(1.0f, 1.0f + __expf(-ao));
            const float cc = fv * c_prev[off] + iv * tz;
            const float nn = fv * n_prev[off] + iv;
            Hout[off] = ov * __fdividef(cc, nn);
        }
    }
}

extern "C" void kernel_launch(void* const* d_in, const int* in_sizes, int n_in,
                              void* d_out, int out_size, void* d_ws, size_t ws_size,
                              hipStream_t stream) {
    const float* x      = (const float*)d_in[0];
    const float* h_prev = (const float*)d_in[1];
    const float* c_prev = (const float*)d_in[2];
    const float* n_prev = (const float*)d_in[3];
    const float* Wz = (const float*)d_in[4];
    const float* Wi = (const float*)d_in[5];
    const float* Wf = (const float*)d_in[6];
    const float* Wo = (const float*)d_in[7];
    const float* bz = (const float*)d_in[8];
    const float* bi = (const float*)d_in[9];
    const float* bf = (const float*)d_in[10];
    const float* bo = (const float*)d_in[11];
    const float* Rz = (const float*)d_in[12];
    const float* Ri = (const float*)d_in[13];
    const float* Rf = (const float*)d_in[14];
    const float* Ro = (const float*)d_in[15];

    _Float16* A  = (_Float16*)d_ws;                       // [B_SZ, K_TOT]
    _Float16* Wb = A + (size_t)B_SZ * K_TOT;              // [N_TOT, K_TOT]

    cast_A_kernel<<<(B_SZ * K_TOT / 8) / 256, 256, 0, stream>>>(x, h_prev, A);
    cast_W_kernel<<<(N_TOT * K_TOT / 8) / 256, 256, 0, stream>>>(
        Wz, Wi, Wf, Wo, Rz, Ri, Rf, Ro, Wb);

    dim3 grid(N_TOT / BN, B_SZ / BM);   // (64, 32) = 2048 blocks
    slstm_gemm_kernel<<<grid, 256, 0, stream>>>(
        A, Wb, c_prev, n_prev, bz, bi, bf, bo, (float*)d_out);
}

// Round 4
// 452.427 us; speedup vs baseline: 1.1425x; 1.0579x over previous
//
#include <hip/hip_runtime.h>
#include <hip/hip_fp16.h>

// Problem constants
#define B_SZ  4096
#define DIN   1024
#define DH    2048
#define K_TOT 3072      // DIN + DH
#define N_TOT 8192      // 4 * DH

// GEMM tile
#define BM 128
#define BN 128          // = 32 hidden units * 4 gates, interleaved [16z|16i|16f|16o] per 64 cols
#define BK 64           // 32 MFMA per wave per barrier pair (AITER-style amortization)

typedef _Float16 half8 __attribute__((ext_vector_type(8)));
typedef float   float4v __attribute__((ext_vector_type(4)));

// ---------- async global->LDS (16B per lane, wave-uniform LDS base) ----------
__device__ __forceinline__ void load_lds16(const void* g, void* l) {
    __builtin_amdgcn_global_load_lds(
        (const __attribute__((address_space(1))) void*)g,
        (__attribute__((address_space(3))) void*)l,
        16, 0, 0);
}

// ---------- fused cast kernel: A-part + W-part in one launch ----------
// blockIdx.x < A_BLOCKS: cast x|h_prev -> A [B_SZ, K_TOT] fp16
// else:                  cast W|R -> Wb [N_TOT, K_TOT] fp16, gate-interleaved @16
//   Wb row n: tile = n>>7; t = n&127; gate g=(t>>4)&3; j = tile*32 + (t>>6)*16 + (t&15)
#define A_BLOCKS ((B_SZ * K_TOT / 8) / 256)
#define W_BLOCKS ((N_TOT * K_TOT / 8) / 256)

__global__ __launch_bounds__(256) void cast_all_kernel(
        const float* __restrict__ x, const float* __restrict__ h,
        const float* __restrict__ Wz, const float* __restrict__ Wi,
        const float* __restrict__ Wf, const float* __restrict__ Wo,
        const float* __restrict__ Rz, const float* __restrict__ Ri,
        const float* __restrict__ Rf, const float* __restrict__ Ro,
        _Float16* __restrict__ A, _Float16* __restrict__ Wb) {
    const float* src;
    _Float16* dst;
    if (blockIdx.x < A_BLOCKS) {
        int idx = (blockIdx.x * 256 + threadIdx.x) * 8;
        int b = idx / K_TOT;
        int c = idx - b * K_TOT;
        src = (c < DIN) ? (x + (size_t)b * DIN + c) : (h + (size_t)b * DH + (c - DIN));
        dst = A + idx;
    } else {
        int idx = ((blockIdx.x - A_BLOCKS) * 256 + threadIdx.x) * 8;
        int n = idx / K_TOT;
        int c = idx - n * K_TOT;
        int t = n & 127;
        int g = (t >> 4) & 3;
        int j = ((n >> 7) << 5) + ((t >> 6) << 4) + (t & 15);
        const float* W = (g == 0) ? Wz : (g == 1) ? Wi : (g == 2) ? Wf : Wo;
        const float* R = (g == 0) ? Rz : (g == 1) ? Ri : (g == 2) ? Rf : Ro;
        src = (c < DIN) ? (W + (size_t)j * DIN + c) : (R + (size_t)j * DH + (c - DIN));
        dst = Wb + idx;
    }
    float4 v0 = *reinterpret_cast<const float4*>(src);
    float4 v1 = *reinterpret_cast<const float4*>(src + 4);
    half8 o;
    o[0] = (_Float16)v0.x; o[1] = (_Float16)v0.y;
    o[2] = (_Float16)v0.z; o[3] = (_Float16)v0.w;
    o[4] = (_Float16)v1.x; o[5] = (_Float16)v1.y;
    o[6] = (_Float16)v1.z; o[7] = (_Float16)v1.w;
    *reinterpret_cast<half8*>(dst) = o;
}

// ---------- fused GEMM + sLSTM pointwise epilogue ----------
// Block: 256 threads = 4 waves arranged 2x2; wave (wm,wn) owns 64x64:
//   4 A-frags x 4 B-frags of 16x16x32 MFMA -> acc[4][4]; BK=64 = 2 k-phases.
// Gate interleave @16: nf IS the gate index, hidden unit j uniform over nf/mf.
//
// LDS swizzle (BK=64, 128B rows): 16B chunk c of row r stored at chunk
// c ^ (r&7). Staging: global k-chunk = (l&7)^((l>>3)&7), lane-constant.
// Fragment read: LDS chunk = (kp*4+quad) ^ (l16&7) -> 2-way (free).
__global__ __launch_bounds__(256) void slstm_gemm_kernel(
        const _Float16* __restrict__ A, const _Float16* __restrict__ Wb,
        const float* __restrict__ c_prev, const float* __restrict__ n_prev,
        const float* __restrict__ bz, const float* __restrict__ bi,
        const float* __restrict__ bf, const float* __restrict__ bo,
        float* __restrict__ Hout) {
    __shared__ __align__(16) _Float16 As[BM * BK];   // 16 KB
    __shared__ __align__(16) _Float16 Bs[BN * BK];   // 16 KB

    const int ntile = blockIdx.x;          // 0..63  (hidden base = 32*ntile)
    const int mtile = blockIdx.y;          // 0..31
    const int tid  = threadIdx.x;
    const int wv   = tid >> 6;
    const int wm   = wv >> 1;              // 0..1
    const int wn   = wv & 1;               // 0..1
    const int l    = tid & 63;
    const int quad = l >> 4;
    const int l16  = l & 15;

    const int m0 = mtile * BM;
    const int n0 = ntile * BN;

    float4v acc[4][4];
#pragma unroll
    for (int i = 0; i < 4; i++)
#pragma unroll
        for (int j = 0; j < 4; j++) acc[i][j] = (float4v){0.f, 0.f, 0.f, 0.f};

    // Staging: tile = 16 KB = 16 chunks of 1KB; wave wv stages chunks
    // {4wv..4wv+3} of both As and Bs. Chunk c = rows c*8..c*8+7 (128B rows).
    // Lane l -> row c*8 + (l>>3), swizzled k-chunk (l&7)^((l>>3)&7).
    const int lrow  = l >> 3;                                  // 0..7
    const int skoff = (((l & 7) ^ (lrow & 7)) * 8);            // elements

    const int r0 = wv * 32 + lrow;       // chunk 4wv+0
    const _Float16* Ag0 = A  + (size_t)(m0 + r0)      * K_TOT + skoff;
    const _Float16* Ag1 = A  + (size_t)(m0 + r0 + 8)  * K_TOT + skoff;
    const _Float16* Ag2 = A  + (size_t)(m0 + r0 + 16) * K_TOT + skoff;
    const _Float16* Ag3 = A  + (size_t)(m0 + r0 + 24) * K_TOT + skoff;
    const _Float16* Bg0 = Wb + (size_t)(n0 + r0)      * K_TOT + skoff;
    const _Float16* Bg1 = Wb + (size_t)(n0 + r0 + 8)  * K_TOT + skoff;
    const _Float16* Bg2 = Wb + (size_t)(n0 + r0 + 16) * K_TOT + skoff;
    const _Float16* Bg3 = Wb + (size_t)(n0 + r0 + 24) * K_TOT + skoff;

    _Float16* AsL0 = As + (wv * 4 + 0) * 512;
    _Float16* AsL1 = As + (wv * 4 + 1) * 512;
    _Float16* AsL2 = As + (wv * 4 + 2) * 512;
    _Float16* AsL3 = As + (wv * 4 + 3) * 512;
    _Float16* BsL0 = Bs + (wv * 4 + 0) * 512;
    _Float16* BsL1 = Bs + (wv * 4 + 1) * 512;
    _Float16* BsL2 = Bs + (wv * 4 + 2) * 512;
    _Float16* BsL3 = Bs + (wv * 4 + 3) * 512;

    // Fragment-read swizzled k-offsets (elements), lane-constant per phase.
    const int kq0 = (((0 * 4 + quad) ^ (l16 & 7)) * 8);
    const int kq1 = (((1 * 4 + quad) ^ (l16 & 7)) * 8);

    for (int kt = 0; kt < K_TOT; kt += BK) {
        load_lds16(Ag0 + kt, AsL0);
        load_lds16(Ag1 + kt, AsL1);
        load_lds16(Ag2 + kt, AsL2);
        load_lds16(Ag3 + kt, AsL3);
        load_lds16(Bg0 + kt, BsL0);
        load_lds16(Bg1 + kt, BsL1);
        load_lds16(Bg2 + kt, BsL2);
        load_lds16(Bg3 + kt, BsL3);
        __syncthreads();

#pragma unroll
        for (int kp = 0; kp < 2; kp++) {
            const int kq = kp ? kq1 : kq0;
            half8 afr[4], bfr[4];
#pragma unroll
            for (int mf = 0; mf < 4; mf++)
                afr[mf] = *reinterpret_cast<const half8*>(As + (wm * 64 + mf * 16 + l16) * BK + kq);
#pragma unroll
            for (int nf = 0; nf < 4; nf++)
                bfr[nf] = *reinterpret_cast<const half8*>(Bs + (wn * 64 + nf * 16 + l16) * BK + kq);

#pragma unroll
            for (int mf = 0; mf < 4; mf++)
#pragma unroll
                for (int nf = 0; nf < 4; nf++)
                    acc[mf][nf] = __builtin_amdgcn_mfma_f32_16x16x32_f16(afr[mf], bfr[nf], acc[mf][nf], 0, 0, 0);
        }
        __syncthreads();
    }

    // Epilogue: C/D layout col=lane&15, row=quad*4+reg. nf = gate.
    const int j = ntile * 32 + wn * 16 + l16;   // hidden unit, uniform over nf/mf
    const float bzv = bz[j], biv = bi[j], bfv = bf[j], bov = bo[j];
#pragma unroll
    for (int mf = 0; mf < 4; mf++) {
#pragma unroll
        for (int r = 0; r < 4; r++) {
            const int row = m0 + wm * 64 + mf * 16 + quad * 4 + r;
            const size_t off = (size_t)row * DH + j;
            const float az  = acc[mf][0][r] + bzv;
            const float ai  = acc[mf][1][r] + biv;
            const float af_ = acc[mf][2][r] + bfv;
            const float ao  = acc[mf][3][r] + bov;
            // tanh via exp, sign-safe (e2 <= 1 always; no inf/inf)
            const float ax = fabsf(az);
            const float e2 = __expf(-2.0f * ax);
            float tz = __fdividef(1.0f - e2, 1.0f + e2);
            tz = (az >= 0.0f) ? tz : -tz;
            const float iv = __expf(ai);
            const float fv = __expf(af_);
            const float ov = __fdividef(1.0f, 1.0f + __expf(-ao));
            const float cc = fv * c_prev[off] + iv * tz;
            const float nn = fv * n_prev[off] + iv;
            Hout[off] = ov * __fdividef(cc, nn);
        }
    }
}

extern "C" void kernel_launch(void* const* d_in, const int* in_sizes, int n_in,
                              void* d_out, int out_size, void* d_ws, size_t ws_size,
                              hipStream_t stream) {
    const float* x      = (const float*)d_in[0];
    const float* h_prev = (const float*)d_in[1];
    const float* c_prev = (const float*)d_in[2];
    const float* n_prev = (const float*)d_in[3];
    const float* Wz = (const float*)d_in[4];
    const float* Wi = (const float*)d_in[5];
    const float* Wf = (const float*)d_in[6];
    const float* Wo = (const float*)d_in[7];
    const float* bz = (const float*)d_in[8];
    const float* bi = (const float*)d_in[9];
    const float* bf = (const float*)d_in[10];
    const float* bo = (const float*)d_in[11];
    const float* Rz = (const float*)d_in[12];
    const float* Ri = (const float*)d_in[13];
    const float* Rf = (const float*)d_in[14];
    const float* Ro = (const float*)d_in[15];

    _Float16* A  = (_Float16*)d_ws;                       // [B_SZ, K_TOT]
    _Float16* Wb = A + (size_t)B_SZ * K_TOT;              // [N_TOT, K_TOT]

    cast_all_kernel<<<A_BLOCKS + W_BLOCKS, 256, 0, stream>>>(
        x, h_prev, Wz, Wi, Wf, Wo, Rz, Ri, Rf, Ro, A, Wb);

    dim3 grid(N_TOT / BN, B_SZ / BM);   // (64, 32) = 2048 blocks
    slstm_gemm_kernel<<<grid, 256, 0, stream>>>(
        A, Wb, c_prev, n_prev, bz, bi, bf, bo, (float*)d_out);
}